// Round 8
// baseline (1759.702 us; speedup 1.0000x reference)
//
#include <hip/hip_runtime.h>

#define NATOM 65536
#define MNBR 12
#define NMROW (NATOM*MNBR)      // 786432
#define ORIG 92
#define NBRF 41
#define AF 64
#define HF 128
#define NCRYS 1024
#define EPSBN 1e-5f
#define NBP 48                  // padded edge width (bf16)
#define CGRID 2048
#define NTASK 16384             // 48-row tasks; 8 per block exactly

typedef __attribute__((ext_vector_type(8))) short short8;
typedef __attribute__((ext_vector_type(4))) short shortx4;
typedef __attribute__((ext_vector_type(4))) float floatx4;

__device__ __forceinline__ float softplusf_(float x){
    return fmaxf(x,0.f) + __logf(1.f + __expf(-fabsf(x)));
}
__device__ __forceinline__ float sigmoidf_(float x){
    return __builtin_amdgcn_rcpf(1.f + __expf(-x));
}
__device__ __forceinline__ short f2bf(float x){
    unsigned u = __float_as_uint(x);
    u += 0x7fffu + ((u >> 16) & 1u);   // RNE
    return (short)(u >> 16);
}
__device__ __forceinline__ unsigned packbf(float f, float g){
    return (unsigned)(unsigned short)f2bf(f) | ((unsigned)(unsigned short)f2bf(g) << 16);
}

// ---------------- embedding: afea = atom_fea @ emb_w + emb_b ----------------
__global__ void k_embed(const float* __restrict__ atom_fea, const float* __restrict__ emb_w,
                        const float* __restrict__ emb_b, float* __restrict__ afea,
                        short* __restrict__ abf)
{
    __shared__ float wl[ORIG*AF];
    __shared__ float bl[AF];
    __shared__ float rows[4*ORIG];
    int tid = threadIdx.x;
    for (int i = tid; i < ORIG*AF; i += 256) wl[i] = emb_w[i];
    if (tid < AF) bl[tid] = emb_b[tid];
    __syncthreads();
    for (int t = blockIdx.x; t < NATOM/4; t += gridDim.x) {
        for (int i = tid; i < 4*ORIG; i += 256) rows[i] = atom_fea[t*4*ORIG + i];
        __syncthreads();
        int r = tid >> 6, c = tid & 63;
        float acc = bl[c];
        const float* rp = &rows[r*ORIG];
        #pragma unroll 4
        for (int k = 0; k < ORIG; ++k) acc += rp[k] * wl[k*AF + c];
        int n = t*4 + r;
        afea[n*AF + c] = acc;
        abf[n*AF + c] = f2bf(acc);
        __syncthreads();
    }
}

// ------------- one-time: nbr_fea fp32 [NM][41] -> bf16 padded [NM][48] -------------
__global__ void k_prep_nbr(const float* __restrict__ nbr_fea, short* __restrict__ nbf)
{
    int g = blockIdx.x*256 + threadIdx.x;   // NMROW*6 threads
    int row = g / 6, c = g % 6;
    const float* src = nbr_fea + (long)row*NBRF + c*8;
    short8 v = {0,0,0,0,0,0,0,0};
    if (c < 5) {
        #pragma unroll
        for (int j = 0; j < 8; ++j) v[j] = f2bf(src[j]);
    } else {
        v[0] = f2bf(src[0]);                // k=40 only
    }
    *(short8*)(nbf + (long)g*8) = v;
}

// ------------- per-layer: W fp32 [169][128] -> bf16 fragments [ks][q][c][j] -------------
__global__ void k_prep_w(const float* __restrict__ W, short* __restrict__ wt2)
{
    int g = blockIdx.x*256 + threadIdx.x;   // 24576 threads
    int j = g & 7, c = (g >> 3) & 127, q = (g >> 10) & 3, ks = g >> 12;
    int k = ks*32 + q*8 + j;
    wt2[g] = (k < 169) ? f2bf(W[k*128 + c]) : (short)0;
}

// ---------------- conv GEMM: gated = [self|nbr|edge] @ W + b ----------------
// Task = 48 rows (4 atoms) x 128 ch; wave owns 16 paired channels. Double-
// buffered LDS staging, software-pipelined. 8 tasks/block, one barrier/task.
// MODE 0: stats1 only. MODE 1: BN1+gate+m-sum. MODE 2: stats1 + packed gated.
template<int MODE>
__global__ __launch_bounds__(256, 5)
void k_conv(const short* __restrict__ abf, const short* __restrict__ nbf,
            const int* __restrict__ nbr_idx, const short* __restrict__ wt2,
            const float* __restrict__ bias,
            float* __restrict__ stats1, const float* __restrict__ bn1ss,
            float* __restrict__ nsum, float* __restrict__ stats2,
            unsigned* __restrict__ gpair)
{
    __shared__ __align__(16) short stg[2][6432];
    __shared__ float pbuf[(MODE==1) ? 4*12*17 : 4];

    int tid = threadIdx.x;
    int lane = tid & 63, wave = tid >> 6;
    int l15 = lane & 15, q = lane >> 4;
    int cf = wave*16 + l15;
    int cc = 64 + cf;

    short8 wf[6][2];
    #pragma unroll
    for (int ks = 0; ks < 6; ++ks) {
        wf[ks][0] = *(const short8*)(wt2 + ((ks*4+q)*128 + cf)*8);
        wf[ks][1] = *(const short8*)(wt2 + ((ks*4+q)*128 + cc)*8);
    }
    float bs0 = bias[cf], bs1 = bias[cc];
    float sc0=0.f, sh0=0.f, sc1=0.f, sh1=0.f;
    if (MODE==1) { sc0=bn1ss[cf]; sh0=bn1ss[128+cf]; sc1=bn1ss[cc]; sh1=bn1ss[128+cc]; }

    int kind[3], ldso[3], nrow[3]; long gco[3];
    #pragma unroll
    for (int s = 0; s < 3; ++s) {
        int i = tid + s*256;
        if (i < 384)      { kind[s]=0; int row=i>>3, c=i&7; nrow[s]=row; ldso[s]=row*72+c*8; gco[s]=c*8; }
        else if (i < 672) { kind[s]=1; int j=i-384; int row=j/6, c=j%6; nrow[s]=0; ldso[s]=3456+row*56+c*8; gco[s]=row*48+c*8; }
        else if (i < 704) { kind[s]=2; int j=i-672; int a=j>>3, c=j&7; nrow[s]=0; ldso[s]=6144+a*72+c*8; gco[s]=a*64+c*8; }
        else              { kind[s]=3; nrow[s]=0; ldso[s]=0; gco[s]=0; }
    }
    int art[3], nvo[3], evo[3], svo[3];
    #pragma unroll
    for (int rt = 0; rt < 3; ++rt) {
        int r = rt*16 + l15;
        art[rt] = r/12;
        nvo[rt] = r*72 + q*8;
        evo[rt] = 3456 + r*56 + q*8;
        svo[rt] = 6144 + art[rt]*72 + q*8;
    }

    float s_acc[2]={0.f,0.f}, s2_acc[2]={0.f,0.f};
    float st2s = 0.f, st2q = 0.f;
    const short8 zf = {0,0,0,0,0,0,0,0};
    float* pb = pbuf + ((MODE==1) ? wave*(12*17) : 0);
    const int bt = blockIdx.x;

    int nid[3];
    short8 hold[3];
    #pragma unroll
    for (int s = 0; s < 3; ++s)
        if (kind[s]==0) nid[s] = nbr_idx[bt*48 + nrow[s]];
    #pragma unroll
    for (int s = 0; s < 3; ++s) {
        if (kind[s]==0)      hold[s] = *(const short8*)(abf + (unsigned)nid[s]*64u + gco[s]);
        else if (kind[s]==1) hold[s] = *(const short8*)(nbf + (long)bt*2304 + gco[s]);
        else if (kind[s]==2) hold[s] = *(const short8*)(abf + (unsigned)bt*256u + gco[s]);
    }
    #pragma unroll
    for (int s = 0; s < 3; ++s)
        if (kind[s]==0) nid[s] = nbr_idx[(bt+CGRID)*48 + nrow[s]];
    #pragma unroll
    for (int s = 0; s < 3; ++s)
        if (kind[s] < 3) *(short8*)(&stg[0][0] + ldso[s]) = hold[s];
    __syncthreads();

    #pragma unroll 2
    for (int k = 0; k < 8; ++k) {
        int b = bt + k*CGRID;
        if (k < 7) {
            int bn = b + CGRID;
            #pragma unroll
            for (int s = 0; s < 3; ++s) {
                if (kind[s]==0)      hold[s] = *(const short8*)(abf + (unsigned)nid[s]*64u + gco[s]);
                else if (kind[s]==1) hold[s] = *(const short8*)(nbf + (long)bn*2304 + gco[s]);
                else if (kind[s]==2) hold[s] = *(const short8*)(abf + (unsigned)bn*256u + gco[s]);
            }
            if (k < 6) {
                #pragma unroll
                for (int s = 0; s < 3; ++s)
                    if (kind[s]==0) nid[s] = nbr_idx[(bn+CGRID)*48 + nrow[s]];
            }
        }

        const short* sb = &stg[k & 1][0];
        floatx4 acc[3][2];
        #pragma unroll
        for (int rt=0; rt<3; ++rt) {
            acc[rt][0] = (floatx4){bs0,bs0,bs0,bs0};
            acc[rt][1] = (floatx4){bs1,bs1,bs1,bs1};
        }
        #pragma unroll
        for (int rt = 0; rt < 3; ++rt) {
            short8 sv0 = *(const short8*)(sb + svo[rt]);
            short8 sv1 = *(const short8*)(sb + svo[rt] + 32);
            short8 nv0 = *(const short8*)(sb + nvo[rt]);
            short8 nv1 = *(const short8*)(sb + nvo[rt] + 32);
            short8 ev0 = *(const short8*)(sb + evo[rt]);
            short8 ev1 = (q < 2) ? *(const short8*)(sb + evo[rt] + 32) : zf;
            #pragma unroll
            for (int ct = 0; ct < 2; ++ct) {
                acc[rt][ct] = __builtin_amdgcn_mfma_f32_16x16x32_bf16(sv0, wf[0][ct], acc[rt][ct], 0,0,0);
                acc[rt][ct] = __builtin_amdgcn_mfma_f32_16x16x32_bf16(sv1, wf[1][ct], acc[rt][ct], 0,0,0);
                acc[rt][ct] = __builtin_amdgcn_mfma_f32_16x16x32_bf16(nv0, wf[2][ct], acc[rt][ct], 0,0,0);
                acc[rt][ct] = __builtin_amdgcn_mfma_f32_16x16x32_bf16(nv1, wf[3][ct], acc[rt][ct], 0,0,0);
                acc[rt][ct] = __builtin_amdgcn_mfma_f32_16x16x32_bf16(ev0, wf[4][ct], acc[rt][ct], 0,0,0);
                acc[rt][ct] = __builtin_amdgcn_mfma_f32_16x16x32_bf16(ev1, wf[5][ct], acc[rt][ct], 0,0,0);
            }
        }

        if (MODE != 1) {
            #pragma unroll
            for (int ct=0; ct<2; ++ct)
                #pragma unroll
                for (int rt=0; rt<3; ++rt)
                    #pragma unroll
                    for (int r=0; r<4; ++r) {
                        float v = acc[rt][ct][r];
                        s_acc[ct] += v; s2_acc[ct] += v*v;
                    }
        }
        if (MODE == 2) {
            // streaming store, keep out of L2 (preserve abf gather set)
            #pragma unroll
            for (int rt=0; rt<3; ++rt) {
                unsigned base = (unsigned)(b*48 + rt*16 + q*4)*64u + (unsigned)(wave*16 + l15);
                #pragma unroll
                for (int r=0; r<4; ++r)
                    __builtin_nontemporal_store(packbf(acc[rt][0][r], acc[rt][1][r]),
                                                gpair + base + (unsigned)r*64u);
            }
        }
        if (MODE == 1) {
            #pragma unroll
            for (int rt=0; rt<3; ++rt) {
                float part = 0.f;
                #pragma unroll
                for (int r=0; r<4; ++r) {
                    float f = acc[rt][0][r]*sc0 + sh0;
                    float g = acc[rt][1][r]*sc1 + sh1;
                    part += sigmoidf_(f) * softplusf_(g);
                }
                pb[(rt*4+q)*17 + l15] = part;
            }
            int a = lane >> 4, c16 = lane & 15;
            float s = pb[(3*a+0)*17 + c16] + pb[(3*a+1)*17 + c16] + pb[(3*a+2)*17 + c16];
            nsum[(b*4 + a)*AF + wave*16 + c16] = s;
            st2s += s; st2q += s*s;
        }

        if (k < 7) {
            short* db = &stg[(k + 1) & 1][0];
            #pragma unroll
            for (int s = 0; s < 3; ++s)
                if (kind[s] < 3) *(short8*)(db + ldso[s]) = hold[s];
        }
        __syncthreads();
    }

    if (MODE != 1) {
        #pragma unroll
        for (int ct=0; ct<2; ++ct) {
            float s = s_acc[ct], s2 = s2_acc[ct];
            s  += __shfl_xor(s, 16);  s  += __shfl_xor(s, 32);
            s2 += __shfl_xor(s2, 16); s2 += __shfl_xor(s2, 32);
            if (q == 0) {
                int c = ct ? cc : cf;
                atomicAdd(&stats1[c], s);
                atomicAdd(&stats1[128 + c], s2);
            }
        }
    } else {
        st2s += __shfl_xor(st2s, 16); st2s += __shfl_xor(st2s, 32);
        st2q += __shfl_xor(st2q, 16); st2q += __shfl_xor(st2q, 32);
        if (q == 0) {
            atomicAdd(&stats2[cf], st2s);
            atomicAdd(&stats2[64 + cf], st2q);
        }
    }
}

// -------- elementwise pass 2 (big-ws path): BN1 + sigmoid*softplus + m-sum --------
__global__ __launch_bounds__(256, 4)
void k_gate(const unsigned* __restrict__ gpair, const float* __restrict__ bn1ss,
            float* __restrict__ nsum, float* __restrict__ stats2)
{
    __shared__ float red[2][4][64];
    int tid = threadIdx.x;
    int lane = tid & 63, wave = tid >> 6;
    float scf = bn1ss[lane],    shf = bn1ss[128+lane];
    float scc = bn1ss[64+lane], shc = bn1ss[192+lane];
    float st2s = 0.f, st2q = 0.f;
    int a0 = blockIdx.x*64 + wave;
    for (int j = 0; j < 16; ++j) {
        int atom = a0 + j*4;
        const unsigned* gp = gpair + (unsigned)atom*12u*64u + lane;
        unsigned u[12];
        #pragma unroll
        for (int i = 0; i < 12; ++i) u[i] = __builtin_nontemporal_load(gp + i*64);
        float s = 0.f;
        #pragma unroll
        for (int i = 0; i < 12; ++i) {
            float f = __uint_as_float(u[i] << 16);
            float g = __uint_as_float(u[i] & 0xffff0000u);
            f = f*scf + shf;
            g = g*scc + shc;
            s += sigmoidf_(f) * softplusf_(g);
        }
        nsum[atom*AF + lane] = s;
        st2s += s; st2q += s*s;
    }
    red[0][wave][lane] = st2s;
    red[1][wave][lane] = st2q;
    __syncthreads();
    if (tid < 64) {
        float s  = red[0][0][tid] + red[0][1][tid] + red[0][2][tid] + red[0][3][tid];
        float s2 = red[1][0][tid] + red[1][1][tid] + red[1][2][tid] + red[1][3][tid];
        atomicAdd(&stats2[tid], s);
        atomicAdd(&stats2[64 + tid], s2);
    }
}

__global__ void k_bn1fin(const float* __restrict__ stats1, const float* __restrict__ g,
                         const float* __restrict__ b, float* __restrict__ bn1ss)
{
    int c = threadIdx.x;
    float mean = stats1[c] * (1.f/NMROW);
    float var  = stats1[128+c] * (1.f/NMROW) - mean*mean;
    float scale = g[c] * rsqrtf(var + EPSBN);
    bn1ss[c] = scale;
    bn1ss[128+c] = b[c] - mean*scale;
}

// vectorized x4: thread handles 4 consecutive channels of one atom
__global__ void k_update(float* __restrict__ afea, short* __restrict__ abf,
                         const float* __restrict__ nsum,
                         const float* __restrict__ stats2,
                         const float* __restrict__ g2, const float* __restrict__ b2)
{
    int g = blockIdx.x*256 + threadIdx.x;   // 4096 blocks; element base g*4
    int c0 = (g*4) & 63;
    float4 ns4 = ((const float4*)nsum)[g];
    float4 a4  = ((const float4*)afea)[g];
    float o[4]; shortx4 ob;
    #pragma unroll
    for (int i = 0; i < 4; ++i) {
        int c = c0 + i;
        float mean = stats2[c] * (1.f/NATOM);
        float var  = stats2[64+c] * (1.f/NATOM) - mean*mean;
        float scale = g2[c]*rsqrtf(var + EPSBN);
        float shift = b2[c] - mean*scale;
        float ns = ((const float*)&ns4)[i]*scale + shift;
        float a = ((const float*)&a4)[i];
        float v = softplusf_(a + ns) + a;
        o[i] = v; ob[i] = f2bf(v);
    }
    ((float4*)afea)[g] = (float4){o[0],o[1],o[2],o[3]};
    *(shortx4*)(abf + (long)g*4) = ob;
}

__global__ void k_pool(const float* __restrict__ afea, const int* __restrict__ cidx,
                       float* __restrict__ pool, float* __restrict__ cnt)
{
    int g = blockIdx.x*256 + threadIdx.x;   // 1024 blocks
    int c = g & 63; int chunk = g >> 6;     // 4096 chunks x 16 atoms
    float run = 0.f, rc = 0.f; int cur = -1;
    for (int i = 0; i < 16; ++i) {
        int a = chunk*16 + i;
        int cr = cidx[a];
        float v = afea[a*64 + c];
        if (cr != cur) {
            if (cur >= 0) { atomicAdd(&pool[cur*64+c], run); if (c==0) atomicAdd(&cnt[cur], rc); }
            run = 0.f; rc = 0.f; cur = cr;
        }
        run += v; rc += 1.f;
    }
    atomicAdd(&pool[cur*64+c], run); if (c==0) atomicAdd(&cnt[cur], rc);
}

__global__ void k_head(const float* __restrict__ pool, const float* __restrict__ cnt,
                       const float* __restrict__ fc1w, const float* __restrict__ fc1b,
                       const float* __restrict__ o1w, const float* __restrict__ o1b,
                       const float* __restrict__ o2w, const float* __restrict__ o2b,
                       float* __restrict__ dout)
{
    __shared__ float spv[64], crys[128], h1[64];
    int b = blockIdx.x, tid = threadIdx.x;
    if (tid < 64) {
        float ct = fmaxf(cnt[b], 1.f);
        spv[tid] = softplusf_(pool[b*64+tid] / ct);
    }
    __syncthreads();
    float a = fc1b[tid];
    for (int k = 0; k < 64; ++k) a += spv[k] * fc1w[k*128 + tid];
    float v = softplusf_(a);
    crys[tid] = v;
    dout[NCRYS + b*128 + tid] = v;
    __syncthreads();
    if (tid < 64) {
        float a2 = o1b[tid];
        for (int k = 0; k < 128; ++k) a2 += crys[k] * o1w[k*64 + tid];
        h1[tid] = softplusf_(a2) * o2w[tid];
    }
    __syncthreads();
    if (tid == 0) {
        float s = o2b[0];
        for (int j = 0; j < 64; ++j) s += h1[j];
        dout[b] = s;
    }
}

extern "C" void kernel_launch(void* const* d_in, const int* in_sizes, int n_in,
                              void* d_out, int out_size, void* d_ws, size_t ws_size,
                              hipStream_t stream)
{
    const float* atom_fea = (const float*)d_in[0];
    const float* nbr_fea  = (const float*)d_in[1];
    const int*   nbr_idx  = (const int*)d_in[2];
    const int*   cidx     = (const int*)d_in[3];
    const float* emb_w    = (const float*)d_in[4];
    const float* emb_b    = (const float*)d_in[5];
    const float* cfw      = (const float*)d_in[6];
    const float* cfb      = (const float*)d_in[7];
    const float* bn1g     = (const float*)d_in[8];
    const float* bn1b     = (const float*)d_in[9];
    const float* bn2g     = (const float*)d_in[10];
    const float* bn2b     = (const float*)d_in[11];
    const float* fc1w     = (const float*)d_in[12];
    const float* fc1b     = (const float*)d_in[13];
    const float* o1w      = (const float*)d_in[14];
    const float* o1b      = (const float*)d_in[15];
    const float* o2w      = (const float*)d_in[16];
    const float* o2b      = (const float*)d_in[17];

    float* ws    = (float*)d_ws;
    float* afea  = ws;                         // 16 MB
    float* nsum  = ws + 4194304;               // 16 MB
    short* abf   = (short*)(ws + 8388608);     // 8 MB
    short* nbf   = (short*)(ws + 10485760);    // 75.5 MB
    short* wt2   = (short*)(ws + 29360128);    // 48 KB
    float* stats = ws + 29372416;              // 3 x 640
    float* pool  = ws + 29374336;              // 256 KB
    float* cnt   = ws + 29439872;              // 4 KB
    unsigned* gpair = (unsigned*)(ws + 29440896); // 201 MB (big-ws path only)

    bool big = ws_size >= (size_t)(29440896 + 50331648) * 4;

    hipMemsetAsync(stats, 0, (1920 + 65536 + 1024)*sizeof(float), stream);

    k_prep_nbr<<<(NMROW*6)/256, 256, 0, stream>>>(nbr_fea, nbf);
    k_embed<<<2048, 256, 0, stream>>>(atom_fea, emb_w, emb_b, afea, abf);

    for (int L = 0; L < 3; ++L) {
        float* st1 = stats + L*640;
        float* ss  = st1 + 256;
        float* st2 = st1 + 512;
        k_prep_w<<<96, 256, 0, stream>>>(cfw + L*169*128, wt2);
        if (big) {
            k_conv<2><<<CGRID, 256, 0, stream>>>(abf, nbf, nbr_idx, wt2, cfb + L*128,
                                                 st1, nullptr, nullptr, nullptr, gpair);
            k_bn1fin<<<1, 128, 0, stream>>>(st1, bn1g + L*128, bn1b + L*128, ss);
            k_gate<<<NATOM/64, 256, 0, stream>>>(gpair, ss, nsum, st2);
        } else {
            k_conv<0><<<CGRID, 256, 0, stream>>>(abf, nbf, nbr_idx, wt2, cfb + L*128,
                                                 st1, nullptr, nullptr, nullptr, nullptr);
            k_bn1fin<<<1, 128, 0, stream>>>(st1, bn1g + L*128, bn1b + L*128, ss);
            k_conv<1><<<CGRID, 256, 0, stream>>>(abf, nbf, nbr_idx, wt2, cfb + L*128,
                                                 nullptr, ss, nsum, st2, nullptr);
        }
        k_update<<<4096, 256, 0, stream>>>(afea, abf, nsum, st2, bn2g + L*64, bn2b + L*64);
    }
    k_pool<<<1024, 256, 0, stream>>>(afea, cidx, pool, cnt);
    k_head<<<NCRYS, 128, 0, stream>>>(pool, cnt, fc1w, fc1b, o1w, o1b, o2w, o2b, (float*)d_out);
}

// Round 9
// 845.132 us; speedup vs baseline: 2.0822x; 2.0822x over previous
//
#include <hip/hip_runtime.h>

#define NATOM 65536
#define MNBR 12
#define NMROW (NATOM*MNBR)      // 786432
#define ORIG 92
#define NBRF 41
#define AF 64
#define HF 128
#define NCRYS 1024
#define EPSBN 1e-5f
#define NBP 48                  // padded edge width (bf16)
#define CGRID 2048
#define NTASK 16384             // 48-row tasks; 8 per block exactly

typedef __attribute__((ext_vector_type(8))) short short8;
typedef __attribute__((ext_vector_type(4))) short shortx4;
typedef __attribute__((ext_vector_type(4))) float floatx4;

__device__ __forceinline__ float softplusf_(float x){
    return fmaxf(x,0.f) + __logf(1.f + __expf(-fabsf(x)));
}
__device__ __forceinline__ float sigmoidf_(float x){
    return __builtin_amdgcn_rcpf(1.f + __expf(-x));
}
__device__ __forceinline__ short f2bf(float x){
    unsigned u = __float_as_uint(x);
    u += 0x7fffu + ((u >> 16) & 1u);   // RNE
    return (short)(u >> 16);
}

// ---------------- embedding: afea = atom_fea @ emb_w + emb_b ----------------
__global__ void k_embed(const float* __restrict__ atom_fea, const float* __restrict__ emb_w,
                        const float* __restrict__ emb_b, float* __restrict__ afea,
                        short* __restrict__ abf)
{
    __shared__ float wl[ORIG*AF];
    __shared__ float bl[AF];
    __shared__ float rows[4*ORIG];
    int tid = threadIdx.x;
    for (int i = tid; i < ORIG*AF; i += 256) wl[i] = emb_w[i];
    if (tid < AF) bl[tid] = emb_b[tid];
    __syncthreads();
    for (int t = blockIdx.x; t < NATOM/4; t += gridDim.x) {
        for (int i = tid; i < 4*ORIG; i += 256) rows[i] = atom_fea[t*4*ORIG + i];
        __syncthreads();
        int r = tid >> 6, c = tid & 63;
        float acc = bl[c];
        const float* rp = &rows[r*ORIG];
        #pragma unroll 4
        for (int k = 0; k < ORIG; ++k) acc += rp[k] * wl[k*AF + c];
        int n = t*4 + r;
        afea[n*AF + c] = acc;
        abf[n*AF + c] = f2bf(acc);
        __syncthreads();
    }
}

// ------------- one-time: nbr_fea fp32 [NM][41] -> bf16 padded [NM][48] -------------
__global__ void k_prep_nbr(const float* __restrict__ nbr_fea, short* __restrict__ nbf)
{
    int g = blockIdx.x*256 + threadIdx.x;   // NMROW*6 threads
    int row = g / 6, c = g % 6;
    const float* src = nbr_fea + (long)row*NBRF + c*8;
    short8 v = {0,0,0,0,0,0,0,0};
    if (c < 5) {
        #pragma unroll
        for (int j = 0; j < 8; ++j) v[j] = f2bf(src[j]);
    } else {
        v[0] = f2bf(src[0]);                // k=40 only
    }
    *(short8*)(nbf + (long)g*8) = v;
}

// ------------- per-layer: W fp32 [169][128] -> bf16 fragments [ks][q][c][j] -------------
__global__ void k_prep_w(const float* __restrict__ W, short* __restrict__ wt2)
{
    int g = blockIdx.x*256 + threadIdx.x;   // 24576 threads
    int j = g & 7, c = (g >> 3) & 127, q = (g >> 10) & 3, ks = g >> 12;
    int k = ks*32 + q*8 + j;
    wt2[g] = (k < 169) ? f2bf(W[k*128 + c]) : (short)0;
}

// ---------------- conv GEMM: gated = [self|nbr|edge] @ W + b ----------------
// 512-thread block (8 waves), task = 48 rows (4 atoms) x 128 ch.
// Waves 0-3: filt channels wgrp*16+l15 (0..63); waves 4-7: core 64+wgrp*16+l15.
// Per-wave regs: wf[6]=24, acc[3]=12, hold[2]=16 -> fits 4 waves/SIMD (cap 128).
// Double-buffered LDS staging, software-pipelined, idx prefetched 2 ahead.
// PASS2=0: per-channel sum/sumsq -> stats1 (1 barrier/task).
// PASS2=1: BN1; filt waves -> sigmoid -> xbuf; core waves multiply softplus,
//          m-sum -> nsum; stats2 (2 barriers/task).
template<int PASS2>
__global__ __launch_bounds__(512, 4)
void k_conv(const short* __restrict__ abf, const short* __restrict__ nbf,
            const int* __restrict__ nbr_idx, const short* __restrict__ wt2,
            const float* __restrict__ bias,
            float* __restrict__ stats1, const float* __restrict__ bn1ss,
            float* __restrict__ nsum, float* __restrict__ stats2)
{
    __shared__ __align__(16) short stg[2][6432];   // nbr 48x72 @0, edge 48x56 @3456, self 4x72 @6144
    __shared__ float xbuf[PASS2 ? 48*68 : 4];      // filt sigmoid exchange [row][68]
    __shared__ float pbuf[PASS2 ? 4*12*17 : 4];    // core-wave-private m-sum partials

    int tid = threadIdx.x;
    int lane = tid & 63, wave = tid >> 6;
    int l15 = lane & 15, q = lane >> 4;
    int isCore = wave >> 2;       // 0 = filt, 1 = core
    int wgrp = wave & 3;
    int cp = wgrp*16 + l15;       // pair channel (0..63)
    int ch = isCore*64 + cp;      // actual channel (0..127)

    short8 wf[6];
    #pragma unroll
    for (int ks = 0; ks < 6; ++ks)
        wf[ks] = *(const short8*)(wt2 + ((ks*4+q)*128 + ch)*8);
    float bs = bias[ch];
    float sc = 0.f, sh = 0.f;
    if (PASS2) { sc = bn1ss[ch]; sh = bn1ss[128+ch]; }

    // staging slot constants (2 slots/thread, 704 lane-loads/task)
    int kind[2], ldso[2], nrow[2], gco[2];
    #pragma unroll
    for (int s = 0; s < 2; ++s) {
        int i = tid + s*512;
        if (i < 384)      { kind[s]=0; int row=i>>3, c=i&7; nrow[s]=row; ldso[s]=row*72+c*8; gco[s]=c*8; }
        else if (i < 672) { kind[s]=1; int j=i-384; int row=j/6, c=j%6; nrow[s]=0; ldso[s]=3456+row*56+c*8; gco[s]=row*48+c*8; }
        else if (i < 704) { kind[s]=2; int j=i-672; int a=j>>3, c=j&7; nrow[s]=0; ldso[s]=6144+a*72+c*8; gco[s]=a*64+c*8; }
        else              { kind[s]=3; nrow[s]=0; ldso[s]=0; gco[s]=0; }
    }
    // per-wave LDS read offsets
    int nvo[3], evo[3], svo[3];
    #pragma unroll
    for (int rt = 0; rt < 3; ++rt) {
        int r = rt*16 + l15;
        nvo[rt] = r*72 + q*8;
        evo[rt] = 3456 + r*56 + q*8;
        svo[rt] = 6144 + (r/12)*72 + q*8;
    }

    float s_acc = 0.f, s2_acc = 0.f;
    float st2s = 0.f, st2q = 0.f;
    const short8 zf = {0,0,0,0,0,0,0,0};
    float* pb = pbuf + (PASS2 ? wgrp*(12*17) : 0);
    const int bt = blockIdx.x;

    // ---- pipeline prologue: stage task 0, prefetch idx(task 1) ----
    int nid = 0;
    short8 hold[2];
    if (kind[0]==0) nid = nbr_idx[bt*48 + nrow[0]];
    #pragma unroll
    for (int s = 0; s < 2; ++s) {
        if (kind[s]==0)      hold[s] = *(const short8*)(abf + (unsigned)nid*64u + gco[s]);
        else if (kind[s]==1) hold[s] = __builtin_nontemporal_load((const short8*)(nbf + (long)bt*2304 + gco[s]));
        else if (kind[s]==2) hold[s] = *(const short8*)(abf + (unsigned)bt*256u + gco[s]);
    }
    if (kind[0]==0) nid = nbr_idx[(bt+CGRID)*48 + nrow[0]];
    #pragma unroll
    for (int s = 0; s < 2; ++s)
        if (kind[s] < 3) *(short8*)(&stg[0][0] + ldso[s]) = hold[s];
    __syncthreads();

    #pragma unroll 2
    for (int k = 0; k < 8; ++k) {
        int b = bt + k*CGRID;
        // ---- issue next task's loads (overlap with compute below) ----
        if (k < 7) {
            int bn = b + CGRID;
            #pragma unroll
            for (int s = 0; s < 2; ++s) {
                if (kind[s]==0)      hold[s] = *(const short8*)(abf + (unsigned)nid*64u + gco[s]);
                else if (kind[s]==1) hold[s] = __builtin_nontemporal_load((const short8*)(nbf + (long)bn*2304 + gco[s]));
                else if (kind[s]==2) hold[s] = *(const short8*)(abf + (unsigned)bn*256u + gco[s]);
            }
            if (k < 6 && kind[0]==0) nid = nbr_idx[(bn+CGRID)*48 + nrow[0]];
        }

        // ---- compute current task from LDS buffer k&1 ----
        const short* sb = &stg[k & 1][0];
        floatx4 acc[3];
        #pragma unroll
        for (int rt=0; rt<3; ++rt) acc[rt] = (floatx4){bs,bs,bs,bs};
        #pragma unroll
        for (int rt = 0; rt < 3; ++rt) {
            short8 sv0 = *(const short8*)(sb + svo[rt]);
            short8 sv1 = *(const short8*)(sb + svo[rt] + 32);
            short8 nv0 = *(const short8*)(sb + nvo[rt]);
            short8 nv1 = *(const short8*)(sb + nvo[rt] + 32);
            short8 ev0 = *(const short8*)(sb + evo[rt]);
            short8 ev1 = (q < 2) ? *(const short8*)(sb + evo[rt] + 32) : zf;
            acc[rt] = __builtin_amdgcn_mfma_f32_16x16x32_bf16(sv0, wf[0], acc[rt], 0,0,0);
            acc[rt] = __builtin_amdgcn_mfma_f32_16x16x32_bf16(sv1, wf[1], acc[rt], 0,0,0);
            acc[rt] = __builtin_amdgcn_mfma_f32_16x16x32_bf16(nv0, wf[2], acc[rt], 0,0,0);
            acc[rt] = __builtin_amdgcn_mfma_f32_16x16x32_bf16(nv1, wf[3], acc[rt], 0,0,0);
            acc[rt] = __builtin_amdgcn_mfma_f32_16x16x32_bf16(ev0, wf[4], acc[rt], 0,0,0);
            acc[rt] = __builtin_amdgcn_mfma_f32_16x16x32_bf16(ev1, wf[5], acc[rt], 0,0,0);
        }

        if (!PASS2) {
            #pragma unroll
            for (int rt=0; rt<3; ++rt)
                #pragma unroll
                for (int r=0; r<4; ++r) {
                    float v = acc[rt][r];
                    s_acc += v; s2_acc += v*v;
                }
        } else {
            // filt waves: sigmoid(BN(f)) -> xbuf[row][cp]
            if (!isCore) {
                #pragma unroll
                for (int rt=0; rt<3; ++rt)
                    #pragma unroll
                    for (int r=0; r<4; ++r) {
                        int row = rt*16 + q*4 + r;
                        xbuf[row*68 + cp] = sigmoidf_(acc[rt][r]*sc + sh);
                    }
            }
            __syncthreads();
            // core waves: p = xbuf * softplus(BN(g)); 4-row partials; m-sum
            if (isCore) {
                #pragma unroll
                for (int rt=0; rt<3; ++rt) {
                    float part = 0.f;
                    #pragma unroll
                    for (int r=0; r<4; ++r) {
                        int row = rt*16 + q*4 + r;
                        part += xbuf[row*68 + cp] * softplusf_(acc[rt][r]*sc + sh);
                    }
                    pb[(rt*4+q)*17 + l15] = part;
                }
                // wave-private LDS: lgkmcnt ordering suffices, no barrier
                int a = lane >> 4, c16 = lane & 15;
                float s = pb[(3*a+0)*17 + c16] + pb[(3*a+1)*17 + c16] + pb[(3*a+2)*17 + c16];
                nsum[(b*4 + a)*AF + wgrp*16 + c16] = s;
                st2s += s; st2q += s*s;
            }
        }

        // ---- commit next task's staging to the other buffer ----
        if (k < 7) {
            short* db = &stg[(k + 1) & 1][0];
            #pragma unroll
            for (int s = 0; s < 2; ++s)
                if (kind[s] < 3) *(short8*)(db + ldso[s]) = hold[s];
        }
        __syncthreads();
    }

    if (!PASS2) {
        float s = s_acc, s2 = s2_acc;
        s  += __shfl_xor(s, 16);  s  += __shfl_xor(s, 32);
        s2 += __shfl_xor(s2, 16); s2 += __shfl_xor(s2, 32);
        if (q == 0) {
            atomicAdd(&stats1[ch], s);
            atomicAdd(&stats1[128 + ch], s2);
        }
    } else if (isCore) {
        st2s += __shfl_xor(st2s, 16); st2s += __shfl_xor(st2s, 32);
        st2q += __shfl_xor(st2q, 16); st2q += __shfl_xor(st2q, 32);
        if (q == 0) {
            atomicAdd(&stats2[cp], st2s);
            atomicAdd(&stats2[64 + cp], st2q);
        }
    }
}

__global__ void k_bn1fin(const float* __restrict__ stats1, const float* __restrict__ g,
                         const float* __restrict__ b, float* __restrict__ bn1ss)
{
    int c = threadIdx.x;
    float mean = stats1[c] * (1.f/NMROW);
    float var  = stats1[128+c] * (1.f/NMROW) - mean*mean;
    float scale = g[c] * rsqrtf(var + EPSBN);
    bn1ss[c] = scale;
    bn1ss[128+c] = b[c] - mean*scale;
}

// vectorized x4: thread handles 4 consecutive channels of one atom
__global__ void k_update(float* __restrict__ afea, short* __restrict__ abf,
                         const float* __restrict__ nsum,
                         const float* __restrict__ stats2,
                         const float* __restrict__ g2, const float* __restrict__ b2)
{
    int g = blockIdx.x*256 + threadIdx.x;   // 4096 blocks; element base g*4
    int c0 = (g*4) & 63;
    float4 ns4 = ((const float4*)nsum)[g];
    float4 a4  = ((const float4*)afea)[g];
    float o[4]; shortx4 ob;
    #pragma unroll
    for (int i = 0; i < 4; ++i) {
        int c = c0 + i;
        float mean = stats2[c] * (1.f/NATOM);
        float var  = stats2[64+c] * (1.f/NATOM) - mean*mean;
        float scale = g2[c]*rsqrtf(var + EPSBN);
        float shift = b2[c] - mean*scale;
        float ns = ((const float*)&ns4)[i]*scale + shift;
        float a = ((const float*)&a4)[i];
        float v = softplusf_(a + ns) + a;
        o[i] = v; ob[i] = f2bf(v);
    }
    ((float4*)afea)[g] = (float4){o[0],o[1],o[2],o[3]};
    *(shortx4*)(abf + (long)g*4) = ob;
}

__global__ void k_pool(const float* __restrict__ afea, const int* __restrict__ cidx,
                       float* __restrict__ pool, float* __restrict__ cnt)
{
    int g = blockIdx.x*256 + threadIdx.x;   // 1024 blocks
    int c = g & 63; int chunk = g >> 6;     // 4096 chunks x 16 atoms
    float run = 0.f, rc = 0.f; int cur = -1;
    for (int i = 0; i < 16; ++i) {
        int a = chunk*16 + i;
        int cr = cidx[a];
        float v = afea[a*64 + c];
        if (cr != cur) {
            if (cur >= 0) { atomicAdd(&pool[cur*64+c], run); if (c==0) atomicAdd(&cnt[cur], rc); }
            run = 0.f; rc = 0.f; cur = cr;
        }
        run += v; rc += 1.f;
    }
    atomicAdd(&pool[cur*64+c], run); if (c==0) atomicAdd(&cnt[cur], rc);
}

__global__ void k_head(const float* __restrict__ pool, const float* __restrict__ cnt,
                       const float* __restrict__ fc1w, const float* __restrict__ fc1b,
                       const float* __restrict__ o1w, const float* __restrict__ o1b,
                       const float* __restrict__ o2w, const float* __restrict__ o2b,
                       float* __restrict__ dout)
{
    __shared__ float spv[64], crys[128], h1[64];
    int b = blockIdx.x, tid = threadIdx.x;
    if (tid < 64) {
        float ct = fmaxf(cnt[b], 1.f);
        spv[tid] = softplusf_(pool[b*64+tid] / ct);
    }
    __syncthreads();
    float a = fc1b[tid];
    for (int k = 0; k < 64; ++k) a += spv[k] * fc1w[k*128 + tid];
    float v = softplusf_(a);
    crys[tid] = v;
    dout[NCRYS + b*128 + tid] = v;
    __syncthreads();
    if (tid < 64) {
        float a2 = o1b[tid];
        for (int k = 0; k < 128; ++k) a2 += crys[k] * o1w[k*64 + tid];
        h1[tid] = softplusf_(a2) * o2w[tid];
    }
    __syncthreads();
    if (tid == 0) {
        float s = o2b[0];
        for (int j = 0; j < 64; ++j) s += h1[j];
        dout[b] = s;
    }
}

extern "C" void kernel_launch(void* const* d_in, const int* in_sizes, int n_in,
                              void* d_out, int out_size, void* d_ws, size_t ws_size,
                              hipStream_t stream)
{
    const float* atom_fea = (const float*)d_in[0];
    const float* nbr_fea  = (const float*)d_in[1];
    const int*   nbr_idx  = (const int*)d_in[2];
    const int*   cidx     = (const int*)d_in[3];
    const float* emb_w    = (const float*)d_in[4];
    const float* emb_b    = (const float*)d_in[5];
    const float* cfw      = (const float*)d_in[6];
    const float* cfb      = (const float*)d_in[7];
    const float* bn1g     = (const float*)d_in[8];
    const float* bn1b     = (const float*)d_in[9];
    const float* bn2g     = (const float*)d_in[10];
    const float* bn2b     = (const float*)d_in[11];
    const float* fc1w     = (const float*)d_in[12];
    const float* fc1b     = (const float*)d_in[13];
    const float* o1w      = (const float*)d_in[14];
    const float* o1b      = (const float*)d_in[15];
    const float* o2w      = (const float*)d_in[16];
    const float* o2b      = (const float*)d_in[17];

    float* ws    = (float*)d_ws;
    float* afea  = ws;                         // 16 MB
    float* nsum  = ws + 4194304;               // 16 MB
    short* abf   = (short*)(ws + 8388608);     // 8 MB
    short* nbf   = (short*)(ws + 10485760);    // 75.5 MB
    short* wt2   = (short*)(ws + 29360128);    // 48 KB
    float* stats = ws + 29372416;              // 3 x 640
    float* pool  = ws + 29374336;              // 256 KB
    float* cnt   = ws + 29439872;              // 4 KB

    hipMemsetAsync(stats, 0, (1920 + 65536 + 1024)*sizeof(float), stream);

    k_prep_nbr<<<(NMROW*6)/256, 256, 0, stream>>>(nbr_fea, nbf);
    k_embed<<<2048, 256, 0, stream>>>(atom_fea, emb_w, emb_b, afea, abf);

    for (int L = 0; L < 3; ++L) {
        float* st1 = stats + L*640;
        float* ss  = st1 + 256;
        float* st2 = st1 + 512;
        k_prep_w<<<96, 256, 0, stream>>>(cfw + L*169*128, wt2);
        k_conv<0><<<CGRID, 512, 0, stream>>>(abf, nbf, nbr_idx, wt2, cfb + L*128,
                                             st1, nullptr, nullptr, nullptr);
        k_bn1fin<<<1, 128, 0, stream>>>(st1, bn1g + L*128, bn1b + L*128, ss);
        k_conv<1><<<CGRID, 512, 0, stream>>>(abf, nbf, nbr_idx, wt2, cfb + L*128,
                                             nullptr, ss, nsum, st2);
        k_update<<<4096, 256, 0, stream>>>(afea, abf, nsum, st2, bn2g + L*64, bn2b + L*64);
    }
    k_pool<<<1024, 256, 0, stream>>>(afea, cidx, pool, cnt);
    k_head<<<NCRYS, 128, 0, stream>>>(pool, cnt, fc1w, fc1b, o1w, o1b, o2w, o2b, (float*)d_out);
}